// Round 19
// baseline (258.311 us; speedup 1.0000x reference)
//
#include <hip/hip_runtime.h>
#include <hip/hip_bf16.h>
#include <hip/hip_cooperative_groups.h>

// Problem constants (shapes fixed by the reference)
#define XS   2
#define NP   96
#define NLAY 3
#define NXI  (XS*NP)   // 192
#define VBF_ARR (XS*256*96)   // 49152 ushorts per component array

namespace cgx = cooperative_groups;

// packed (rep,dim) index tables: 16 = 1+3+5+7 entries
__constant__ int P2R_c[16] = {0, 1,1,1, 2,2,2,2,2, 3,3,3,3,3,3,3};
__constant__ int P2D_c[16] = {0, 0,1,2, 0,1,2,3,4, 0,1,2,3,4,5,6};
__constant__ int DIMS_c[4] = {1,3,5,7};
__constant__ int OFF_c[4]  = {0,1,4,9};

typedef __attribute__((ext_vector_type(8))) short bf16x8;
typedef __attribute__((ext_vector_type(4))) float f32x4;

__device__ inline float2 cmadd(float2 acc, float2 a, float2 b){
    acc.x += a.x*b.x - a.y*b.y;
    acc.y += a.x*b.y + a.y*b.x;
    return acc;
}
__device__ inline unsigned short f2bf(float v){
    __hip_bfloat16 h = __float2bfloat16(v);
    union { __hip_bfloat16 h; unsigned short u; } cv; cv.h = h; return cv.u;
}
__device__ inline float bf2f(unsigned short u){
    union { unsigned short u; __hip_bfloat16 h; } cv; cv.u = u;
    return __bfloat162float(cv.h);
}

// Single cooperative kernel: grid 192 blocks x 512 threads (co-resident).
// Prologue: PKbf + Vbf0 pack (grid-split) + per-block dX (layer-invariant).
// Per layer: cgf rebuild -> filters straight into bf16 Abuf -> MFMA T ->
// MFMA S -> W (Vbf_out or d_out). grid.sync() between layers.
__global__ __launch_bounds__(512)
void fused_kernel(const float* __restrict__ cg,
                  const float* __restrict__ f,
                  const float* __restrict__ Vin,
                  const float* __restrict__ X,
                  const float* __restrict__ W,
                  unsigned short* __restrict__ PKbf,   // [6][64][256] bf16
                  unsigned short* __restrict__ VbfA,   // [4][x][n][k] bf16
                  unsigned short* __restrict__ VbfB,
                  float* __restrict__ Dout)
{
    __shared__ float2 dX_s[NP][7];                             // 5376 B
    __shared__ float2 cgf_s[784];                              // 6272 B
    __shared__ __align__(16) unsigned short Abuf[6][16][104];  // 19968 B (aliased by S_s)
    __shared__ __align__(16) unsigned short T2buf[4][16][264]; // 33792 B
    float2* S_s = (float2*)&Abuf[0][0][0];                     // 8192 B

    cgx::grid_group grid = cgx::this_grid();

    const int tid = threadIdx.x;
    const int xi = blockIdx.x;
    const int x = xi / NP, i = xi % NP;

    // ---- prologue A: grid-split prep of PKbf and Vbf0 (into VbfA)
    {
        const int gidx = xi*512 + tid;    // 0 .. 98303
        if (gidx < 16384){
            int id = gidx;                // = qg*256 + lm
            int lm = id & 255;
            int qg = id >> 8;
            int ls = lm >> 4, mt = lm & 15;
            int qr = qg >> 2, g = qg & 3;
            int l = P2R_c[ls], s = P2D_c[ls];
            int m = P2R_c[mt], t = P2D_c[mt];
            int q = P2R_c[qr], r = P2D_c[qr];
            size_t co = (((((((size_t)g*4 + l)*7 + s)*4 + m)*7 + t)*4 + q)*7 + r);
            float re = cg[co*2], im = cg[co*2+1];
            unsigned short rh = f2bf(re), rl = f2bf(re - bf2f(rh));
            unsigned short ih = f2bf(im), il = f2bf(im - bf2f(ih));
            PKbf[0*16384 + id] = rh;
            PKbf[1*16384 + id] = rl;
            PKbf[2*16384 + id] = ih;
            PKbf[3*16384 + id] = il;
            PKbf[4*16384 + id] = ih ^ 0x8000;
            PKbf[5*16384 + id] = il ^ 0x8000;
        } else if (gidx < 65536){
            int id = gidx - 16384;        // = (x*256+n)*96 + kj
            int kj = id % 96;
            int n  = (id / 96) % 256;
            int xx = id / (96*256);
            int mt = n >> 4, c = n & 15;
            int m = P2R_c[mt], t = P2D_c[mt];
            const float* p = Vin + ((((size_t)(xx*NP + kj)*4 + m)*16 + c)*7 + t)*2;
            float re = p[0], im = p[1];
            unsigned short h;
            h = f2bf(re); VbfA[0*VBF_ARR + id] = h;
            VbfA[1*VBF_ARR + id] = f2bf(re - bf2f(h));
            h = f2bf(im); VbfA[2*VBF_ARR + id] = h;
            VbfA[3*VBF_ARR + id] = f2bf(im - bf2f(h));
        }
    }
    // ---- prologue B: dX for this xi (layer-invariant)
    for (int e = tid; e < NP*7; e += 512){
        int j = e / 7, s = e % 7;
        const float* Xj = X + (((size_t)x*NP + j)*7 + s)*2;
        const float* Xi = X + (((size_t)x*NP + i)*7 + s)*2;
        dX_s[j][s] = make_float2(Xj[0]-Xi[0], Xj[1]-Xi[1]);
    }
    __threadfence();
    grid.sync();

    const int w    = tid >> 6;
    const int lane = tid & 63;
    const int lrow = lane & 15;          // A row / B col / D col
    const int kb   = (lane >> 4) * 8;    // k sub-offset within K=32 step

    for (int k = 0; k < NLAY; ++k){
        const unsigned short* Vbf_in  = (k & 1) ? VbfB : VbfA;
        unsigned short*       Vbf_out = (k & 1) ? VbfA : VbfB;
        const float* W_k = W + (size_t)k*4*16*4*16*2;

        // ---- cgf for layer k (784 x 4 cmadd)
        for (int u = tid; u < 784; u += 512){
            int qr = u / 49, st = u % 49;
            int s = st / 7, t = st % 7;
            int q = P2R_c[qr], r = P2D_c[qr];
            float2 acc = make_float2(0.f, 0.f);
            #pragma unroll
            for (int g = 0; g < 4; ++g){
                const float* cgp = cg + (((((((size_t)g*4+3)*7 + s)*4 + 3)*7 + t)*4 + q)*7 + r)*2;
                const float* fp  = f + ((k*4 + q)*4 + g)*2;
                acc = cmadd(acc, make_float2(cgp[0], cgp[1]), make_float2(fp[0], fp[1]));
            }
            cgf_s[u] = acc;
        }
        __syncthreads();

        // ---- filters straight into bf16 hi/lo Abuf
        for (int e = tid; e < NP*16; e += 512){
            int j = e >> 4, qr = e & 15;
            const float2* cb = cgf_s + qr*49;
            float2 acc = make_float2(0.f, 0.f);
            #pragma unroll
            for (int s = 0; s < 7; ++s){
                float2 inner = make_float2(0.f, 0.f);
                #pragma unroll
                for (int t = 0; t < 7; ++t)
                    inner = cmadd(inner, cb[s*7 + t], dX_s[j][t]);
                acc = cmadd(acc, dX_s[j][s], inner);
            }
            if (qr >= 9){ float2 dv = dX_s[j][qr-9]; acc.x += dv.x; acc.y += dv.y; }
            unsigned short h = f2bf(acc.x);
            Abuf[0][qr][j] = h;
            Abuf[1][qr][j] = f2bf(acc.x - bf2f(h));
            h = f2bf(acc.y);
            unsigned short lo = f2bf(acc.y - bf2f(h));
            Abuf[2][qr][j] = h;
            Abuf[3][qr][j] = lo;
            Abuf[4][qr][j] = h  ^ 0x8000;   // -Fi (exact)
            Abuf[5][qr][j] = lo ^ 0x8000;
        }
        __syncthreads();

        // ---- phase T (MFMA): T[ls][n] = sum_j F[j][ls]*V[j][n] (complex)
        {
            f32x4 accR[2], accI[2];
            #pragma unroll
            for (int nt = 0; nt < 2; ++nt){
                accR[nt] = (f32x4){0.f,0.f,0.f,0.f};
                accI[nt] = (f32x4){0.f,0.f,0.f,0.f};
            }
            const unsigned short* Vrh = Vbf_in + 0*VBF_ARR + (size_t)x*256*96;
            const unsigned short* Vrl = Vbf_in + 1*VBF_ARR + (size_t)x*256*96;
            const unsigned short* Vih = Vbf_in + 2*VBF_ARR + (size_t)x*256*96;
            const unsigned short* Vil = Vbf_in + 3*VBF_ARR + (size_t)x*256*96;
            #pragma unroll
            for (int kt = 0; kt < 3; ++kt){
                const int ka = kt*32 + kb;
                bf16x8 frh = *(const bf16x8*)&Abuf[0][lrow][ka];
                bf16x8 frl = *(const bf16x8*)&Abuf[1][lrow][ka];
                bf16x8 fih = *(const bf16x8*)&Abuf[2][lrow][ka];
                bf16x8 fil = *(const bf16x8*)&Abuf[3][lrow][ka];
                bf16x8 nfh = *(const bf16x8*)&Abuf[4][lrow][ka];
                bf16x8 nfl = *(const bf16x8*)&Abuf[5][lrow][ka];
                #pragma unroll
                for (int nt = 0; nt < 2; ++nt){
                    const int n = w*32 + nt*16 + lrow;
                    const size_t bo = (size_t)n*96 + ka;
                    bf16x8 vrh = *(const bf16x8*)(Vrh + bo);
                    bf16x8 vrl = *(const bf16x8*)(Vrl + bo);
                    bf16x8 vih = *(const bf16x8*)(Vih + bo);
                    bf16x8 vil = *(const bf16x8*)(Vil + bo);
                    accR[nt] = __builtin_amdgcn_mfma_f32_16x16x32_bf16(frh, vrh, accR[nt], 0,0,0);
                    accR[nt] = __builtin_amdgcn_mfma_f32_16x16x32_bf16(frh, vrl, accR[nt], 0,0,0);
                    accR[nt] = __builtin_amdgcn_mfma_f32_16x16x32_bf16(frl, vrh, accR[nt], 0,0,0);
                    accR[nt] = __builtin_amdgcn_mfma_f32_16x16x32_bf16(nfh, vih, accR[nt], 0,0,0);
                    accR[nt] = __builtin_amdgcn_mfma_f32_16x16x32_bf16(nfh, vil, accR[nt], 0,0,0);
                    accR[nt] = __builtin_amdgcn_mfma_f32_16x16x32_bf16(nfl, vih, accR[nt], 0,0,0);
                    accI[nt] = __builtin_amdgcn_mfma_f32_16x16x32_bf16(frh, vih, accI[nt], 0,0,0);
                    accI[nt] = __builtin_amdgcn_mfma_f32_16x16x32_bf16(frh, vil, accI[nt], 0,0,0);
                    accI[nt] = __builtin_amdgcn_mfma_f32_16x16x32_bf16(frl, vih, accI[nt], 0,0,0);
                    accI[nt] = __builtin_amdgcn_mfma_f32_16x16x32_bf16(fih, vrh, accI[nt], 0,0,0);
                    accI[nt] = __builtin_amdgcn_mfma_f32_16x16x32_bf16(fih, vrl, accI[nt], 0,0,0);
                    accI[nt] = __builtin_amdgcn_mfma_f32_16x16x32_bf16(fil, vrh, accI[nt], 0,0,0);
                }
            }
            // store straight to bf16 hi/lo B-operand: c = lrow, lm = ls*16 + mt
            #pragma unroll
            for (int nt = 0; nt < 2; ++nt){
                #pragma unroll
                for (int r = 0; r < 4; ++r){
                    const int lmp = ((lane>>4)*4 + r)*16 + (w*2 + nt);
                    float tr = accR[nt][r], ti = accI[nt][r];
                    unsigned short h = f2bf(tr);
                    T2buf[0][lrow][lmp] = h;
                    T2buf[1][lrow][lmp] = f2bf(tr - bf2f(h));
                    h = f2bf(ti);
                    T2buf[2][lrow][lmp] = h;
                    T2buf[3][lrow][lmp] = f2bf(ti - bf2f(h));
                }
            }
        }
        __syncthreads();

        // ---- phase S (MFMA): S[qg][c] = sum_lm PK^T[qg][lm]*T2[lm][c] (complex)
        {
            const int qtile = w & 3;
            const int kh    = w >> 2;
            f32x4 sR = (f32x4){0.f,0.f,0.f,0.f};
            f32x4 sI = (f32x4){0.f,0.f,0.f,0.f};
            #pragma unroll
            for (int kt4 = 0; kt4 < 4; ++kt4){
                const int kt = kh*4 + kt4;
                const int ka = kt*32 + kb;
                const size_t arow = (size_t)(qtile*16 + lrow)*256 + ka;
                bf16x8 prh = *(const bf16x8*)(PKbf + 0*16384 + arow);
                bf16x8 prl = *(const bf16x8*)(PKbf + 1*16384 + arow);
                bf16x8 pih = *(const bf16x8*)(PKbf + 2*16384 + arow);
                bf16x8 pil = *(const bf16x8*)(PKbf + 3*16384 + arow);
                bf16x8 pnh = *(const bf16x8*)(PKbf + 4*16384 + arow);
                bf16x8 pnl = *(const bf16x8*)(PKbf + 5*16384 + arow);
                bf16x8 trh = *(const bf16x8*)&T2buf[0][lrow][ka];
                bf16x8 trl = *(const bf16x8*)&T2buf[1][lrow][ka];
                bf16x8 tih = *(const bf16x8*)&T2buf[2][lrow][ka];
                bf16x8 til = *(const bf16x8*)&T2buf[3][lrow][ka];
                sR = __builtin_amdgcn_mfma_f32_16x16x32_bf16(prh, trh, sR, 0,0,0);
                sR = __builtin_amdgcn_mfma_f32_16x16x32_bf16(prh, trl, sR, 0,0,0);
                sR = __builtin_amdgcn_mfma_f32_16x16x32_bf16(prl, trh, sR, 0,0,0);
                sR = __builtin_amdgcn_mfma_f32_16x16x32_bf16(pnh, tih, sR, 0,0,0);
                sR = __builtin_amdgcn_mfma_f32_16x16x32_bf16(pnh, til, sR, 0,0,0);
                sR = __builtin_amdgcn_mfma_f32_16x16x32_bf16(pnl, tih, sR, 0,0,0);
                sI = __builtin_amdgcn_mfma_f32_16x16x32_bf16(prh, tih, sI, 0,0,0);
                sI = __builtin_amdgcn_mfma_f32_16x16x32_bf16(prh, til, sI, 0,0,0);
                sI = __builtin_amdgcn_mfma_f32_16x16x32_bf16(prl, tih, sI, 0,0,0);
                sI = __builtin_amdgcn_mfma_f32_16x16x32_bf16(pih, trh, sI, 0,0,0);
                sI = __builtin_amdgcn_mfma_f32_16x16x32_bf16(pih, trl, sI, 0,0,0);
                sI = __builtin_amdgcn_mfma_f32_16x16x32_bf16(pil, trh, sI, 0,0,0);
            }
            // staged K-half reduction into S_s[qg*16 + c]  (S_s aliases dead Abuf)
            if (kh == 0){
                #pragma unroll
                for (int r = 0; r < 4; ++r)
                    S_s[((size_t)qtile*16 + (lane>>4)*4 + r)*16 + lrow] =
                        make_float2(sR[r], sI[r]);
            }
            __syncthreads();
            if (kh == 1){
                #pragma unroll
                for (int r = 0; r < 4; ++r){
                    const size_t si = ((size_t)qtile*16 + (lane>>4)*4 + r)*16 + lrow;
                    float2 sp = S_s[si];
                    sp.x += sR[r]; sp.y += sI[r];
                    S_s[si] = sp;
                }
            }
            __syncthreads();
        }

        // ---- phase W
        if (tid < 256){
            const int qr2 = tid >> 4, d = tid & 15;
            const int q = P2R_c[qr2];
            float2 acc = make_float2(0.f, 0.f);
            const float2* Wb = (const float2*)W_k + (size_t)q*16*4*16 + d;
            #pragma unroll 4
            for (int c = 0; c < 16; ++c){
                #pragma unroll
                for (int g = 0; g < 4; ++g){
                    acc = cmadd(acc, S_s[((size_t)qr2*4 + g)*16 + c], Wb[(c*4 + g)*16]);
                }
            }
            if (k == NLAY-1){
                const int r = P2D_c[qr2];
                ((float2*)Dout)[((size_t)xi*4 + q)*112 + d*7 + r] = acc;
            } else {
                const size_t vo = ((size_t)x*256 + tid)*96 + i;
                unsigned short h;
                h = f2bf(acc.x); Vbf_out[0*VBF_ARR + vo] = h;
                Vbf_out[1*VBF_ARR + vo] = f2bf(acc.x - bf2f(h));
                h = f2bf(acc.y); Vbf_out[2*VBF_ARR + vo] = h;
                Vbf_out[3*VBF_ARR + vo] = f2bf(acc.y - bf2f(h));
            }
        } else if (k == NLAY-1){
            // zero the 192 invalid (r >= DIMS[q]) slots; disjoint from valid writes
            const int u = tid - 256;
            if (u < 192){
                int q, base, span;
                if (u < 96)      { q = 0; base = 0;   span = 6; }
                else if (u < 160){ q = 1; base = 96;  span = 4; }
                else             { q = 2; base = 160; span = 2; }
                const int v = u - base;
                const int d = v / span;
                const int r = DIMS_c[q] + v % span;
                ((float2*)Dout)[((size_t)xi*4 + q)*112 + d*7 + r] = make_float2(0.f, 0.f);
            }
        }

        if (k < NLAY-1){
            __threadfence();
            grid.sync();
        }
    }
}

extern "C" void kernel_launch(void* const* d_in, const int* in_sizes, int n_in,
                              void* d_out, int out_size, void* d_ws, size_t ws_size,
                              hipStream_t stream) {
    const float* X  = (const float*)d_in[0];
    // d_in[1] is 'l' (always 3, hardcoded)
    const float* V  = (const float*)d_in[2];
    const float* cg = (const float*)d_in[3];
    const float* f  = (const float*)d_in[4];
    const float* W  = (const float*)d_in[5];
    // d_in[6] is C4 (plain complex product, hardcoded)

    // ws layout (floats): PKbf 49152 | VbfA 98304 | VbfB 98304
    float* ws    = (float*)d_ws;
    unsigned short* PKbf = (unsigned short*)ws;
    unsigned short* VbfA = (unsigned short*)(ws + 49152);
    unsigned short* VbfB = (unsigned short*)(ws + 49152 + 98304);
    float* Dout = (float*)d_out;

    void* args[] = {
        (void*)&cg, (void*)&f, (void*)&V, (void*)&X, (void*)&W,
        (void*)&PKbf, (void*)&VbfA, (void*)&VbfB, (void*)&Dout
    };
    hipLaunchCooperativeKernel((const void*)fused_kernel,
                               dim3(NXI), dim3(512), args, 0, stream);
}

// Round 20
// 71.956 us; speedup vs baseline: 3.5898x; 3.5898x over previous
//
#include <hip/hip_runtime.h>
#include <hip/hip_bf16.h>

// Problem constants (shapes fixed by the reference)
#define XS   2
#define NP   96
#define NLAY 3
#define NXI  (XS*NP)   // 192
#define VBF_ARR (XS*256*96)   // 49152 ushorts per component array

// packed (rep,dim) index tables: 16 = 1+3+5+7 entries
__constant__ int P2R_c[16] = {0, 1,1,1, 2,2,2,2,2, 3,3,3,3,3,3,3};
__constant__ int P2D_c[16] = {0, 0,1,2, 0,1,2,3,4, 0,1,2,3,4,5,6};
__constant__ int DIMS_c[4] = {1,3,5,7};
__constant__ int OFF_c[4]  = {0,1,4,9};

typedef __attribute__((ext_vector_type(8))) short bf16x8;
typedef __attribute__((ext_vector_type(4))) float f32x4;

__device__ inline float2 cmadd(float2 acc, float2 a, float2 b){
    acc.x += a.x*b.x - a.y*b.y;
    acc.y += a.x*b.y + a.y*b.x;
    return acc;
}
__device__ inline unsigned short f2bf(float v){
    __hip_bfloat16 h = __float2bfloat16(v);
    union { __hip_bfloat16 h; unsigned short u; } cv; cv.h = h; return cv.u;
}
__device__ inline float bf2f(unsigned short u){
    union { unsigned short u; __hip_bfloat16 h; } cv; cv.u = u;
    return __bfloat162float(cv.h);
}

// prep: 256 blocks x 256 threads, exactly 65536 elements:
//   [0,16384):       PKbf[6][qg][lm] bf16 hi/lo (S-phase A-operand)
//   [16384,65536):   Vbf0 pack: V -> bf16 hi/lo [arr][x][n=mtc][k=j]
__global__ __launch_bounds__(256)
void prep_kernel(const float* __restrict__ cg,
                 const float* __restrict__ Vin,
                 unsigned short* __restrict__ PKbf,
                 unsigned short* __restrict__ Vbf0){
    int idx = blockIdx.x*256 + threadIdx.x;
    if (idx < 16384){
        int id = idx;              // = qg*256 + lm
        int lm = id & 255;
        int qg = id >> 8;
        int ls = lm >> 4, mt = lm & 15;
        int qr = qg >> 2, g = qg & 3;
        int l = P2R_c[ls], s = P2D_c[ls];
        int m = P2R_c[mt], t = P2D_c[mt];
        int q = P2R_c[qr], r = P2D_c[qr];
        size_t co = (((((((size_t)g*4 + l)*7 + s)*4 + m)*7 + t)*4 + q)*7 + r);
        float re = cg[co*2], im = cg[co*2+1];
        unsigned short rh = f2bf(re), rl = f2bf(re - bf2f(rh));
        unsigned short ih = f2bf(im), il = f2bf(im - bf2f(ih));
        PKbf[0*16384 + id] = rh;
        PKbf[1*16384 + id] = rl;
        PKbf[2*16384 + id] = ih;
        PKbf[3*16384 + id] = il;
        PKbf[4*16384 + id] = ih ^ 0x8000;
        PKbf[5*16384 + id] = il ^ 0x8000;
    } else {
        int id = idx - 16384;      // = (x*256+n)*96 + kj
        int kj = id % 96;
        int n  = (id / 96) % 256;
        int x  = id / (96*256);
        int mt = n >> 4, c = n & 15;
        int m = P2R_c[mt], t = P2D_c[mt];
        const float* p = Vin + ((((size_t)(x*NP + kj)*4 + m)*16 + c)*7 + t)*2;
        float re = p[0], im = p[1];
        unsigned short h;
        h = f2bf(re); Vbf0[0*VBF_ARR + id] = h;
        Vbf0[1*VBF_ARR + id] = f2bf(re - bf2f(h));
        h = f2bf(im); Vbf0[2*VBF_ARR + id] = h;
        Vbf0[3*VBF_ARR + id] = f2bf(im - bf2f(h));
    }
}

// TS_kernel: one block per xi, 512 threads (8 waves). Self-contained:
// builds its own filters (dX from X, cgf from cg/f) straight into the
// bf16 hi/lo Abuf -- no filt_g global intermediate.
//  T: M16(ls) x K96(j) x N256(mtc) complex MFMA; B=Vbf (global).
//  S: M64(qg) x K256(lm) x N16(c) complex MFMA; A=PKbf (global), B=T2buf.
//  W: VALU channel mix. LAST=0: emit next layer's Vbf. LAST=1: d_out.
template<int LAST>
__global__ __launch_bounds__(512, 2)
void TS_kernel(const float* __restrict__ X,
               const float* __restrict__ cg,
               const float* __restrict__ f,
               const int LAYK,
               const unsigned short* __restrict__ PKbf,// [6][64][256] bf16
               const float* __restrict__ W_k,          // [q][c][g][d] complex
               const unsigned short* __restrict__ Vbf_in,  // [4][x][n][k] bf16
               unsigned short* __restrict__ Vbf_out,       // next layer (LAST=0)
               float* __restrict__ Dout)               // d_out (LAST=1)
{
    __shared__ float2 dX_s[NP][7];                             // 5376 B
    __shared__ float2 cgf_s[784];                              // 6272 B
    __shared__ __align__(16) unsigned short Abuf[6][16][104];  // 19968 B (aliased by S_s)
    __shared__ __align__(16) unsigned short T2buf[4][16][264]; // 33792 B
    float2* S_s = (float2*)&Abuf[0][0][0];                     // 8192 B

    const int tid = threadIdx.x;
    const int xi = blockIdx.x;
    const int x = xi / NP, i = xi % NP;

    // ---- build dX and cgf (layer LAYK) in LDS
    for (int e = tid; e < NP*7; e += 512){
        int j = e / 7, s = e % 7;
        const float* Xj = X + (((size_t)x*NP + j)*7 + s)*2;
        const float* Xi = X + (((size_t)x*NP + i)*7 + s)*2;
        dX_s[j][s] = make_float2(Xj[0]-Xi[0], Xj[1]-Xi[1]);
    }
    for (int u = tid; u < 784; u += 512){
        int qr = u / 49, st = u % 49;
        int s = st / 7, t = st % 7;
        int q = P2R_c[qr], r = P2D_c[qr];
        float2 acc = make_float2(0.f, 0.f);
        #pragma unroll
        for (int g = 0; g < 4; ++g){
            const float* cgp = cg + (((((((size_t)g*4+3)*7 + s)*4 + 3)*7 + t)*4 + q)*7 + r)*2;
            const float* fp  = f + ((LAYK*4 + q)*4 + g)*2;
            acc = cmadd(acc, make_float2(cgp[0], cgp[1]), make_float2(fp[0], fp[1]));
        }
        cgf_s[u] = acc;
    }
    __syncthreads();

    // ---- filters straight into bf16 hi/lo Abuf
    for (int e = tid; e < NP*16; e += 512){
        int j = e >> 4, qr = e & 15;
        const float2* cb = cgf_s + qr*49;
        float2 acc = make_float2(0.f, 0.f);
        #pragma unroll
        for (int s = 0; s < 7; ++s){
            float2 inner = make_float2(0.f, 0.f);
            #pragma unroll
            for (int t = 0; t < 7; ++t)
                inner = cmadd(inner, cb[s*7 + t], dX_s[j][t]);
            acc = cmadd(acc, dX_s[j][s], inner);
        }
        if (qr >= 9){ float2 dv = dX_s[j][qr-9]; acc.x += dv.x; acc.y += dv.y; }
        unsigned short h = f2bf(acc.x);
        Abuf[0][qr][j] = h;
        Abuf[1][qr][j] = f2bf(acc.x - bf2f(h));
        h = f2bf(acc.y);
        unsigned short lo = f2bf(acc.y - bf2f(h));
        Abuf[2][qr][j] = h;
        Abuf[3][qr][j] = lo;
        Abuf[4][qr][j] = h  ^ 0x8000;   // -Fi (exact)
        Abuf[5][qr][j] = lo ^ 0x8000;
    }
    __syncthreads();

    const int w    = tid >> 6;
    const int lane = tid & 63;
    const int lrow = lane & 15;          // A row / B col / D col
    const int kb   = (lane >> 4) * 8;    // k sub-offset within K=32 step

    // ---- phase T (MFMA): T[ls][n] = sum_j F[j][ls]*V[j][n] (complex)
    {
        f32x4 accR[2], accI[2];
        #pragma unroll
        for (int nt = 0; nt < 2; ++nt){
            accR[nt] = (f32x4){0.f,0.f,0.f,0.f};
            accI[nt] = (f32x4){0.f,0.f,0.f,0.f};
        }
        const unsigned short* Vrh = Vbf_in + 0*VBF_ARR + (size_t)x*256*96;
        const unsigned short* Vrl = Vbf_in + 1*VBF_ARR + (size_t)x*256*96;
        const unsigned short* Vih = Vbf_in + 2*VBF_ARR + (size_t)x*256*96;
        const unsigned short* Vil = Vbf_in + 3*VBF_ARR + (size_t)x*256*96;
        #pragma unroll
        for (int kt = 0; kt < 3; ++kt){
            const int ka = kt*32 + kb;
            bf16x8 frh = *(const bf16x8*)&Abuf[0][lrow][ka];
            bf16x8 frl = *(const bf16x8*)&Abuf[1][lrow][ka];
            bf16x8 fih = *(const bf16x8*)&Abuf[2][lrow][ka];
            bf16x8 fil = *(const bf16x8*)&Abuf[3][lrow][ka];
            bf16x8 nfh = *(const bf16x8*)&Abuf[4][lrow][ka];
            bf16x8 nfl = *(const bf16x8*)&Abuf[5][lrow][ka];
            #pragma unroll
            for (int nt = 0; nt < 2; ++nt){
                const int n = w*32 + nt*16 + lrow;
                const size_t bo = (size_t)n*96 + ka;
                bf16x8 vrh = *(const bf16x8*)(Vrh + bo);
                bf16x8 vrl = *(const bf16x8*)(Vrl + bo);
                bf16x8 vih = *(const bf16x8*)(Vih + bo);
                bf16x8 vil = *(const bf16x8*)(Vil + bo);
                accR[nt] = __builtin_amdgcn_mfma_f32_16x16x32_bf16(frh, vrh, accR[nt], 0,0,0);
                accR[nt] = __builtin_amdgcn_mfma_f32_16x16x32_bf16(frh, vrl, accR[nt], 0,0,0);
                accR[nt] = __builtin_amdgcn_mfma_f32_16x16x32_bf16(frl, vrh, accR[nt], 0,0,0);
                accR[nt] = __builtin_amdgcn_mfma_f32_16x16x32_bf16(nfh, vih, accR[nt], 0,0,0);
                accR[nt] = __builtin_amdgcn_mfma_f32_16x16x32_bf16(nfh, vil, accR[nt], 0,0,0);
                accR[nt] = __builtin_amdgcn_mfma_f32_16x16x32_bf16(nfl, vih, accR[nt], 0,0,0);
                accI[nt] = __builtin_amdgcn_mfma_f32_16x16x32_bf16(frh, vih, accI[nt], 0,0,0);
                accI[nt] = __builtin_amdgcn_mfma_f32_16x16x32_bf16(frh, vil, accI[nt], 0,0,0);
                accI[nt] = __builtin_amdgcn_mfma_f32_16x16x32_bf16(frl, vih, accI[nt], 0,0,0);
                accI[nt] = __builtin_amdgcn_mfma_f32_16x16x32_bf16(fih, vrh, accI[nt], 0,0,0);
                accI[nt] = __builtin_amdgcn_mfma_f32_16x16x32_bf16(fih, vrl, accI[nt], 0,0,0);
                accI[nt] = __builtin_amdgcn_mfma_f32_16x16x32_bf16(fil, vrh, accI[nt], 0,0,0);
            }
        }
        // store straight to bf16 hi/lo B-operand: c = lrow, lm = ls*16 + mt
        #pragma unroll
        for (int nt = 0; nt < 2; ++nt){
            #pragma unroll
            for (int r = 0; r < 4; ++r){
                const int lmp = ((lane>>4)*4 + r)*16 + (w*2 + nt);
                float tr = accR[nt][r], ti = accI[nt][r];
                unsigned short h = f2bf(tr);
                T2buf[0][lrow][lmp] = h;
                T2buf[1][lrow][lmp] = f2bf(tr - bf2f(h));
                h = f2bf(ti);
                T2buf[2][lrow][lmp] = h;
                T2buf[3][lrow][lmp] = f2bf(ti - bf2f(h));
            }
        }
    }
    __syncthreads();

    // ---- phase S (MFMA): S[qg][c] = sum_lm PK^T[qg][lm] * T2[lm][c] (complex)
    {
        const int qtile = w & 3;
        const int kh    = w >> 2;
        f32x4 sR = (f32x4){0.f,0.f,0.f,0.f};
        f32x4 sI = (f32x4){0.f,0.f,0.f,0.f};
        #pragma unroll
        for (int kt4 = 0; kt4 < 4; ++kt4){
            const int kt = kh*4 + kt4;
            const int ka = kt*32 + kb;
            const size_t arow = (size_t)(qtile*16 + lrow)*256 + ka;
            bf16x8 prh = *(const bf16x8*)(PKbf + 0*16384 + arow);
            bf16x8 prl = *(const bf16x8*)(PKbf + 1*16384 + arow);
            bf16x8 pih = *(const bf16x8*)(PKbf + 2*16384 + arow);
            bf16x8 pil = *(const bf16x8*)(PKbf + 3*16384 + arow);
            bf16x8 pnh = *(const bf16x8*)(PKbf + 4*16384 + arow);
            bf16x8 pnl = *(const bf16x8*)(PKbf + 5*16384 + arow);
            bf16x8 trh = *(const bf16x8*)&T2buf[0][lrow][ka];
            bf16x8 trl = *(const bf16x8*)&T2buf[1][lrow][ka];
            bf16x8 tih = *(const bf16x8*)&T2buf[2][lrow][ka];
            bf16x8 til = *(const bf16x8*)&T2buf[3][lrow][ka];
            sR = __builtin_amdgcn_mfma_f32_16x16x32_bf16(prh, trh, sR, 0,0,0);
            sR = __builtin_amdgcn_mfma_f32_16x16x32_bf16(prh, trl, sR, 0,0,0);
            sR = __builtin_amdgcn_mfma_f32_16x16x32_bf16(prl, trh, sR, 0,0,0);
            sR = __builtin_amdgcn_mfma_f32_16x16x32_bf16(pnh, tih, sR, 0,0,0);
            sR = __builtin_amdgcn_mfma_f32_16x16x32_bf16(pnh, til, sR, 0,0,0);
            sR = __builtin_amdgcn_mfma_f32_16x16x32_bf16(pnl, tih, sR, 0,0,0);
            sI = __builtin_amdgcn_mfma_f32_16x16x32_bf16(prh, tih, sI, 0,0,0);
            sI = __builtin_amdgcn_mfma_f32_16x16x32_bf16(prh, til, sI, 0,0,0);
            sI = __builtin_amdgcn_mfma_f32_16x16x32_bf16(prl, tih, sI, 0,0,0);
            sI = __builtin_amdgcn_mfma_f32_16x16x32_bf16(pih, trh, sI, 0,0,0);
            sI = __builtin_amdgcn_mfma_f32_16x16x32_bf16(pih, trl, sI, 0,0,0);
            sI = __builtin_amdgcn_mfma_f32_16x16x32_bf16(pil, trh, sI, 0,0,0);
        }
        // staged K-half reduction into S_s[qg*16 + c]  (S_s aliases dead Abuf)
        if (kh == 0){
            #pragma unroll
            for (int r = 0; r < 4; ++r)
                S_s[((size_t)qtile*16 + (lane>>4)*4 + r)*16 + lrow] =
                    make_float2(sR[r], sI[r]);
        }
        __syncthreads();
        if (kh == 1){
            #pragma unroll
            for (int r = 0; r < 4; ++r){
                const size_t si = ((size_t)qtile*16 + (lane>>4)*4 + r)*16 + lrow;
                float2 sp = S_s[si];
                sp.x += sR[r]; sp.y += sI[r];
                S_s[si] = sp;
            }
        }
        __syncthreads();
    }

    // ---- phase W: out[qr][d] = sum_{c,g} S[qr*4+g][c]*W[q][c][g][d]
    if (tid < 256){
        const int qr2 = tid >> 4, d = tid & 15;
        const int q = P2R_c[qr2];
        float2 acc = make_float2(0.f, 0.f);
        const float2* Wb = (const float2*)W_k + (size_t)q*16*4*16 + d;
        #pragma unroll 4
        for (int c = 0; c < 16; ++c){
            #pragma unroll
            for (int g = 0; g < 4; ++g){
                acc = cmadd(acc, S_s[((size_t)qr2*4 + g)*16 + c], Wb[(c*4 + g)*16]);
            }
        }
        if (LAST){
            const int r = P2D_c[qr2];
            ((float2*)Dout)[((size_t)xi*4 + q)*112 + d*7 + r] = acc;
        } else {
            const size_t vo = ((size_t)x*256 + tid)*96 + i;
            unsigned short h;
            h = f2bf(acc.x); Vbf_out[0*VBF_ARR + vo] = h;
            Vbf_out[1*VBF_ARR + vo] = f2bf(acc.x - bf2f(h));
            h = f2bf(acc.y); Vbf_out[2*VBF_ARR + vo] = h;
            Vbf_out[3*VBF_ARR + vo] = f2bf(acc.y - bf2f(h));
        }
    } else if (LAST){
        // zero the 192 invalid (r >= DIMS[q]) slots; disjoint from valid writes
        const int u = tid - 256;
        if (u < 192){
            int q, base, span;
            if (u < 96)      { q = 0; base = 0;   span = 6; }
            else if (u < 160){ q = 1; base = 96;  span = 4; }
            else             { q = 2; base = 160; span = 2; }
            const int v = u - base;
            const int d = v / span;
            const int r = DIMS_c[q] + v % span;
            ((float2*)Dout)[((size_t)xi*4 + q)*112 + d*7 + r] = make_float2(0.f, 0.f);
        }
    }
}

extern "C" void kernel_launch(void* const* d_in, const int* in_sizes, int n_in,
                              void* d_out, int out_size, void* d_ws, size_t ws_size,
                              hipStream_t stream) {
    const float* X  = (const float*)d_in[0];
    // d_in[1] is 'l' (always 3, hardcoded)
    const float* V  = (const float*)d_in[2];
    const float* cg = (const float*)d_in[3];
    const float* f  = (const float*)d_in[4];
    const float* W  = (const float*)d_in[5];
    // d_in[6] is C4 (plain complex product, hardcoded)

    // ws layout (floats): PKbf 49152 | VbfA 98304 | VbfB 98304
    float* ws    = (float*)d_ws;
    unsigned short* PKbf = (unsigned short*)ws;
    unsigned short* VbfA = (unsigned short*)(ws + 49152);
    unsigned short* VbfB = (unsigned short*)(ws + 49152 + 98304);

    prep_kernel<<<256, 256, 0, stream>>>(cg, V, PKbf, VbfA);

    const float* W0 = W;
    const float* W1 = W + (size_t)1*4*16*4*16*2;
    const float* W2 = W + (size_t)2*4*16*4*16*2;

    TS_kernel<0><<<NXI, 512, 0, stream>>>(X, cg, f, 0, PKbf, W0, VbfA, VbfB, nullptr);
    TS_kernel<0><<<NXI, 512, 0, stream>>>(X, cg, f, 1, PKbf, W1, VbfB, VbfA, nullptr);
    TS_kernel<1><<<NXI, 512, 0, stream>>>(X, cg, f, 2, PKbf, W2, VbfA, VbfB, (float*)d_out);
}

// Round 21
// 71.900 us; speedup vs baseline: 3.5926x; 1.0008x over previous
//
#include <hip/hip_runtime.h>
#include <hip/hip_bf16.h>

// Problem constants (shapes fixed by the reference)
#define XS   2
#define NP   96
#define NLAY 3
#define NXI  (XS*NP)   // 192
#define VBF_ARR (XS*256*96)   // 49152 ushorts per component array

// packed (rep,dim) index tables: 16 = 1+3+5+7 entries
__constant__ int P2R_c[16] = {0, 1,1,1, 2,2,2,2,2, 3,3,3,3,3,3,3};
__constant__ int P2D_c[16] = {0, 0,1,2, 0,1,2,3,4, 0,1,2,3,4,5,6};
__constant__ int DIMS_c[4] = {1,3,5,7};
__constant__ int OFF_c[4]  = {0,1,4,9};

typedef __attribute__((ext_vector_type(8))) short bf16x8;
typedef __attribute__((ext_vector_type(4))) float f32x4;

__device__ inline float2 cmadd(float2 acc, float2 a, float2 b){
    acc.x += a.x*b.x - a.y*b.y;
    acc.y += a.x*b.y + a.y*b.x;
    return acc;
}
__device__ inline unsigned short f2bf(float v){
    __hip_bfloat16 h = __float2bfloat16(v);
    union { __hip_bfloat16 h; unsigned short u; } cv; cv.h = h; return cv.u;
}
__device__ inline float bf2f(unsigned short u){
    union { unsigned short u; __hip_bfloat16 h; } cv; cv.u = u;
    return __bfloat162float(cv.h);
}

// Merged prep+filt kernel. Blocks [0,256): flat prep ranges
//   idx in [0,16384):  PKbf[6][qg][lm] bf16 hi/lo (S-phase A-operand)
//   idx in [16384,65536): Vbf0 pack: V -> bf16 hi/lo [arr][x][n=mtc][k=j]
// Blocks [256, 256+576): filters for (k, xi); cgf computed in-block (tiny).
__global__ __launch_bounds__(256)
void prep_filt_kernel(const float* __restrict__ cg,
                      const float* __restrict__ f,
                      const float* __restrict__ Vin,
                      const float* __restrict__ X,
                      unsigned short* __restrict__ PKbf,
                      unsigned short* __restrict__ Vbf0,
                      float* __restrict__ filt_g)      // [k][xi][96][16] complex
{
    __shared__ float2 cgf_s[784];
    __shared__ float2 dX_s[NP][7];

    const int tid = threadIdx.x;
    if (blockIdx.x < 256){
        int idx = blockIdx.x*256 + tid;
        if (idx < 16384){
            int id = idx;              // = qg*256 + lm
            int lm = id & 255;
            int qg = id >> 8;
            int ls = lm >> 4, mt = lm & 15;
            int qr = qg >> 2, g = qg & 3;
            int l = P2R_c[ls], s = P2D_c[ls];
            int m = P2R_c[mt], t = P2D_c[mt];
            int q = P2R_c[qr], r = P2D_c[qr];
            size_t co = (((((((size_t)g*4 + l)*7 + s)*4 + m)*7 + t)*4 + q)*7 + r);
            float re = cg[co*2], im = cg[co*2+1];
            unsigned short rh = f2bf(re), rl = f2bf(re - bf2f(rh));
            unsigned short ih = f2bf(im), il = f2bf(im - bf2f(ih));
            PKbf[0*16384 + id] = rh;
            PKbf[1*16384 + id] = rl;
            PKbf[2*16384 + id] = ih;
            PKbf[3*16384 + id] = il;
            PKbf[4*16384 + id] = ih ^ 0x8000;
            PKbf[5*16384 + id] = il ^ 0x8000;
        } else {
            int id = idx - 16384;      // = (x*256+n)*96 + kj
            int kj = id % 96;
            int n  = (id / 96) % 256;
            int x  = id / (96*256);
            int mt = n >> 4, c = n & 15;
            int m = P2R_c[mt], t = P2D_c[mt];
            const float* p = Vin + ((((size_t)(x*NP + kj)*4 + m)*16 + c)*7 + t)*2;
            float re = p[0], im = p[1];
            unsigned short h;
            h = f2bf(re); Vbf0[0*VBF_ARR + id] = h;
            Vbf0[1*VBF_ARR + id] = f2bf(re - bf2f(h));
            h = f2bf(im); Vbf0[2*VBF_ARR + id] = h;
            Vbf0[3*VBF_ARR + id] = f2bf(im - bf2f(h));
        }
        return;
    }

    // ---- filter blocks
    const int fb = blockIdx.x - 256;   // k*NXI + xi
    const int k  = fb / NXI;
    const int xi = fb % NXI;
    const int x = xi / NP, i = xi % NP;

    // compute cgf[k] in LDS (784 entries, 4 cmadd each)
    for (int u = tid; u < 784; u += 256){
        int qr = u / 49, st = u % 49;
        int s = st / 7, t = st % 7;
        int q = P2R_c[qr], r = P2D_c[qr];
        float2 acc = make_float2(0.f, 0.f);
        #pragma unroll
        for (int g = 0; g < 4; ++g){
            const float* cgp = cg + (((((((size_t)g*4+3)*7 + s)*4 + 3)*7 + t)*4 + q)*7 + r)*2;
            const float* fp  = f + ((k*4 + q)*4 + g)*2;
            acc = cmadd(acc, make_float2(cgp[0], cgp[1]), make_float2(fp[0], fp[1]));
        }
        cgf_s[u] = acc;
    }
    for (int e = tid; e < NP*7; e += 256){
        int j = e / 7, s = e % 7;
        const float* Xj = X + (((size_t)x*NP + j)*7 + s)*2;
        const float* Xi = X + (((size_t)x*NP + i)*7 + s)*2;
        dX_s[j][s] = make_float2(Xj[0]-Xi[0], Xj[1]-Xi[1]);
    }
    __syncthreads();

    float2* out = (float2*)filt_g + (size_t)fb*NP*16;
    for (int e = tid; e < NP*16; e += 256){
        int j = e >> 4, qr = e & 15;
        const float2* cb = cgf_s + qr*49;
        float2 acc = make_float2(0.f, 0.f);
        #pragma unroll
        for (int s = 0; s < 7; ++s){
            float2 inner = make_float2(0.f, 0.f);
            #pragma unroll
            for (int t = 0; t < 7; ++t)
                inner = cmadd(inner, cb[s*7 + t], dX_s[j][t]);
            acc = cmadd(acc, dX_s[j][s], inner);
        }
        if (qr >= 9){ float2 dv = dX_s[j][qr-9]; acc.x += dv.x; acc.y += dv.y; }
        out[e] = acc;
    }
}

// TS_kernel: one block per xi, 512 threads (8 waves). Both T and S on MFMA.
// PK operands for the S phase are prefetched into registers at kernel entry
// (independent of all prior work) so their latency hides under Abuf + T.
template<int LAST>
__global__ __launch_bounds__(512, 2)
void TS_kernel(const float* __restrict__ filt_gk,      // [xi][96][16] complex
               const unsigned short* __restrict__ PKbf,// [6][64][256] bf16
               const float* __restrict__ W_k,          // [q][c][g][d] complex
               const unsigned short* __restrict__ Vbf_in,  // [4][x][n][k] bf16
               unsigned short* __restrict__ Vbf_out,       // next layer (LAST=0)
               float* __restrict__ Dout)               // d_out (LAST=1)
{
    __shared__ __align__(16) unsigned short Abuf[6][16][104];  // 19968 B (aliased by S_s)
    __shared__ __align__(16) unsigned short T2buf[4][16][264]; // 33792 B
    float2* S_s = (float2*)&Abuf[0][0][0];                     // [qg][c] = 8192 B

    const int tid = threadIdx.x;
    const int xi = blockIdx.x;
    const int x = xi / NP, i = xi % NP;

    const int w    = tid >> 6;
    const int lane = tid & 63;
    const int lrow = lane & 15;          // A row / B col / D col
    const int kb   = (lane >> 4) * 8;    // k sub-offset within K=32 step
    const int qtile = w & 3;
    const int kh    = w >> 2;

    // ---- prefetch ALL S-phase PK operands (depend on nothing; latency
    // hides under the Abuf build + T phase). 24 x bf16x8 = 96 VGPR.
    bf16x8 prh[4], prl[4], pih[4], pil[4], pnh[4], pnl[4];
    #pragma unroll
    for (int kt4 = 0; kt4 < 4; ++kt4){
        const int kt = kh*4 + kt4;
        const int ka = kt*32 + kb;
        const size_t arow = (size_t)(qtile*16 + lrow)*256 + ka;
        prh[kt4] = *(const bf16x8*)(PKbf + 0*16384 + arow);
        prl[kt4] = *(const bf16x8*)(PKbf + 1*16384 + arow);
        pih[kt4] = *(const bf16x8*)(PKbf + 2*16384 + arow);
        pil[kt4] = *(const bf16x8*)(PKbf + 3*16384 + arow);
        pnh[kt4] = *(const bf16x8*)(PKbf + 4*16384 + arow);
        pnl[kt4] = *(const bf16x8*)(PKbf + 5*16384 + arow);
    }

    // build bf16 hi/lo A-operands from fp32 filters (L2-hot, 12 KB)
    for (int e = tid; e < NP*16; e += 512){
        const int j = e >> 4, ls = e & 15;
        float2 fv = ((const float2*)filt_gk)[((size_t)xi*NP + j)*16 + ls];
        unsigned short h = f2bf(fv.x);
        Abuf[0][ls][j] = h;
        Abuf[1][ls][j] = f2bf(fv.x - bf2f(h));
        h = f2bf(fv.y);
        unsigned short lo = f2bf(fv.y - bf2f(h));
        Abuf[2][ls][j] = h;
        Abuf[3][ls][j] = lo;
        Abuf[4][ls][j] = h  ^ 0x8000;   // -Fi (exact)
        Abuf[5][ls][j] = lo ^ 0x8000;
    }
    __syncthreads();

    // ---- phase T (MFMA): T[ls][n] = sum_j F[j][ls]*V[j][n] (complex)
    {
        f32x4 accR[2], accI[2];
        #pragma unroll
        for (int nt = 0; nt < 2; ++nt){
            accR[nt] = (f32x4){0.f,0.f,0.f,0.f};
            accI[nt] = (f32x4){0.f,0.f,0.f,0.f};
        }
        const unsigned short* Vrh = Vbf_in + 0*VBF_ARR + (size_t)x*256*96;
        const unsigned short* Vrl = Vbf_in + 1*VBF_ARR + (size_t)x*256*96;
        const unsigned short* Vih = Vbf_in + 2*VBF_ARR + (size_t)x*256*96;
        const unsigned short* Vil = Vbf_in + 3*VBF_ARR + (size_t)x*256*96;
        #pragma unroll
        for (int kt = 0; kt < 3; ++kt){
            const int ka = kt*32 + kb;
            bf16x8 frh = *(const bf16x8*)&Abuf[0][lrow][ka];
            bf16x8 frl = *(const bf16x8*)&Abuf[1][lrow][ka];
            bf16x8 fih = *(const bf16x8*)&Abuf[2][lrow][ka];
            bf16x8 fil = *(const bf16x8*)&Abuf[3][lrow][ka];
            bf16x8 nfh = *(const bf16x8*)&Abuf[4][lrow][ka];
            bf16x8 nfl = *(const bf16x8*)&Abuf[5][lrow][ka];
            #pragma unroll
            for (int nt = 0; nt < 2; ++nt){
                const int n = w*32 + nt*16 + lrow;
                const size_t bo = (size_t)n*96 + ka;
                bf16x8 vrh = *(const bf16x8*)(Vrh + bo);
                bf16x8 vrl = *(const bf16x8*)(Vrl + bo);
                bf16x8 vih = *(const bf16x8*)(Vih + bo);
                bf16x8 vil = *(const bf16x8*)(Vil + bo);
                accR[nt] = __builtin_amdgcn_mfma_f32_16x16x32_bf16(frh, vrh, accR[nt], 0,0,0);
                accR[nt] = __builtin_amdgcn_mfma_f32_16x16x32_bf16(frh, vrl, accR[nt], 0,0,0);
                accR[nt] = __builtin_amdgcn_mfma_f32_16x16x32_bf16(frl, vrh, accR[nt], 0,0,0);
                accR[nt] = __builtin_amdgcn_mfma_f32_16x16x32_bf16(nfh, vih, accR[nt], 0,0,0);
                accR[nt] = __builtin_amdgcn_mfma_f32_16x16x32_bf16(nfh, vil, accR[nt], 0,0,0);
                accR[nt] = __builtin_amdgcn_mfma_f32_16x16x32_bf16(nfl, vih, accR[nt], 0,0,0);
                accI[nt] = __builtin_amdgcn_mfma_f32_16x16x32_bf16(frh, vih, accI[nt], 0,0,0);
                accI[nt] = __builtin_amdgcn_mfma_f32_16x16x32_bf16(frh, vil, accI[nt], 0,0,0);
                accI[nt] = __builtin_amdgcn_mfma_f32_16x16x32_bf16(frl, vih, accI[nt], 0,0,0);
                accI[nt] = __builtin_amdgcn_mfma_f32_16x16x32_bf16(fih, vrh, accI[nt], 0,0,0);
                accI[nt] = __builtin_amdgcn_mfma_f32_16x16x32_bf16(fih, vrl, accI[nt], 0,0,0);
                accI[nt] = __builtin_amdgcn_mfma_f32_16x16x32_bf16(fil, vrh, accI[nt], 0,0,0);
            }
        }
        // store straight to bf16 hi/lo B-operand: c = lrow, lm = ls*16 + mt
        #pragma unroll
        for (int nt = 0; nt < 2; ++nt){
            #pragma unroll
            for (int r = 0; r < 4; ++r){
                const int lmp = ((lane>>4)*4 + r)*16 + (w*2 + nt);
                float tr = accR[nt][r], ti = accI[nt][r];
                unsigned short h = f2bf(tr);
                T2buf[0][lrow][lmp] = h;
                T2buf[1][lrow][lmp] = f2bf(tr - bf2f(h));
                h = f2bf(ti);
                T2buf[2][lrow][lmp] = h;
                T2buf[3][lrow][lmp] = f2bf(ti - bf2f(h));
            }
        }
    }
    __syncthreads();

    // ---- phase S (MFMA): S[qg][c] = sum_lm PK^T[qg][lm] * T2[lm][c] (complex)
    // PK operands already in registers (prefetched at kernel entry).
    {
        f32x4 sR = (f32x4){0.f,0.f,0.f,0.f};
        f32x4 sI = (f32x4){0.f,0.f,0.f,0.f};
        #pragma unroll
        for (int kt4 = 0; kt4 < 4; ++kt4){
            const int kt = kh*4 + kt4;
            const int ka = kt*32 + kb;
            bf16x8 trh = *(const bf16x8*)&T2buf[0][lrow][ka];
            bf16x8 trl = *(const bf16x8*)&T2buf[1][lrow][ka];
            bf16x8 tih = *(const bf16x8*)&T2buf[2][lrow][ka];
            bf16x8 til = *(const bf16x8*)&T2buf[3][lrow][ka];
            sR = __builtin_amdgcn_mfma_f32_16x16x32_bf16(prh[kt4], trh, sR, 0,0,0);
            sR = __builtin_amdgcn_mfma_f32_16x16x32_bf16(prh[kt4], trl, sR, 0,0,0);
            sR = __builtin_amdgcn_mfma_f32_16x16x32_bf16(prl[kt4], trh, sR, 0,0,0);
            sR = __builtin_amdgcn_mfma_f32_16x16x32_bf16(pnh[kt4], tih, sR, 0,0,0);
            sR = __builtin_amdgcn_mfma_f32_16x16x32_bf16(pnh[kt4], til, sR, 0,0,0);
            sR = __builtin_amdgcn_mfma_f32_16x16x32_bf16(pnl[kt4], tih, sR, 0,0,0);
            sI = __builtin_amdgcn_mfma_f32_16x16x32_bf16(prh[kt4], tih, sI, 0,0,0);
            sI = __builtin_amdgcn_mfma_f32_16x16x32_bf16(prh[kt4], til, sI, 0,0,0);
            sI = __builtin_amdgcn_mfma_f32_16x16x32_bf16(prl[kt4], tih, sI, 0,0,0);
            sI = __builtin_amdgcn_mfma_f32_16x16x32_bf16(pih[kt4], trh, sI, 0,0,0);
            sI = __builtin_amdgcn_mfma_f32_16x16x32_bf16(pih[kt4], trl, sI, 0,0,0);
            sI = __builtin_amdgcn_mfma_f32_16x16x32_bf16(pil[kt4], trh, sI, 0,0,0);
        }
        // staged K-half reduction into S_s[qg*16 + c]  (S_s aliases dead Abuf)
        if (kh == 0){
            #pragma unroll
            for (int r = 0; r < 4; ++r)
                S_s[((size_t)qtile*16 + (lane>>4)*4 + r)*16 + lrow] =
                    make_float2(sR[r], sI[r]);
        }
        __syncthreads();
        if (kh == 1){
            #pragma unroll
            for (int r = 0; r < 4; ++r){
                const size_t si = ((size_t)qtile*16 + (lane>>4)*4 + r)*16 + lrow;
                float2 sp = S_s[si];
                sp.x += sR[r]; sp.y += sI[r];
                S_s[si] = sp;
            }
        }
        __syncthreads();
    }

    // ---- phase W: out[qr][d] = sum_{c,g} S[qr*4+g][c]*W[q][c][g][d]
    if (tid < 256){
        const int qr2 = tid >> 4, d = tid & 15;
        const int q = P2R_c[qr2];
        float2 acc = make_float2(0.f, 0.f);
        const float2* Wb = (const float2*)W_k + (size_t)q*16*4*16 + d;
        #pragma unroll 4
        for (int c = 0; c < 16; ++c){
            #pragma unroll
            for (int g = 0; g < 4; ++g){
                acc = cmadd(acc, S_s[((size_t)qr2*4 + g)*16 + c], Wb[(c*4 + g)*16]);
            }
        }
        if (LAST){
            const int r = P2D_c[qr2];
            ((float2*)Dout)[((size_t)xi*4 + q)*112 + d*7 + r] = acc;
        } else {
            const size_t vo = ((size_t)x*256 + tid)*96 + i;
            unsigned short h;
            h = f2bf(acc.x); Vbf_out[0*VBF_ARR + vo] = h;
            Vbf_out[1*VBF_ARR + vo] = f2bf(acc.x - bf2f(h));
            h = f2bf(acc.y); Vbf_out[2*VBF_ARR + vo] = h;
            Vbf_out[3*VBF_ARR + vo] = f2bf(acc.y - bf2f(h));
        }
    } else if (LAST){
        // zero the 192 invalid (r >= DIMS[q]) slots; disjoint from valid writes
        const int u = tid - 256;
        if (u < 192){
            int q, base, span;
            if (u < 96)      { q = 0; base = 0;   span = 6; }
            else if (u < 160){ q = 1; base = 96;  span = 4; }
            else             { q = 2; base = 160; span = 2; }
            const int v = u - base;
            const int d = v / span;
            const int r = DIMS_c[q] + v % span;
            ((float2*)Dout)[((size_t)xi*4 + q)*112 + d*7 + r] = make_float2(0.f, 0.f);
        }
    }
}

extern "C" void kernel_launch(void* const* d_in, const int* in_sizes, int n_in,
                              void* d_out, int out_size, void* d_ws, size_t ws_size,
                              hipStream_t stream) {
    const float* X  = (const float*)d_in[0];
    // d_in[1] is 'l' (always 3, hardcoded)
    const float* V  = (const float*)d_in[2];
    const float* cg = (const float*)d_in[3];
    const float* f  = (const float*)d_in[4];
    const float* W  = (const float*)d_in[5];
    // d_in[6] is C4 (plain complex product, hardcoded)

    // ws layout (floats): PKbf 49152 | VbfA 98304 | VbfB 98304 | filt_g 1769472
    float* ws    = (float*)d_ws;
    unsigned short* PKbf = (unsigned short*)ws;
    unsigned short* VbfA = (unsigned short*)(ws + 49152);
    unsigned short* VbfB = (unsigned short*)(ws + 49152 + 98304);
    float* filt_g = ws + 49152 + 98304 + 98304;

    prep_filt_kernel<<<256 + NLAY*NXI, 256, 0, stream>>>(cg, f, V, X, PKbf, VbfA, filt_g);

    const float* W0 = W;
    const float* W1 = W + (size_t)1*4*16*4*16*2;
    const float* W2 = W + (size_t)2*4*16*4*16*2;
    const float* f0 = filt_g;
    const float* f1 = filt_g + (size_t)1*NXI*NP*16*2;
    const float* f2 = filt_g + (size_t)2*NXI*NP*16*2;

    TS_kernel<0><<<NXI, 512, 0, stream>>>(f0, PKbf, W0, VbfA, VbfB, nullptr);
    TS_kernel<0><<<NXI, 512, 0, stream>>>(f1, PKbf, W1, VbfB, VbfA, nullptr);
    TS_kernel<1><<<NXI, 512, 0, stream>>>(f2, PKbf, W2, VbfA, VbfB, (float*)d_out);
}

// Round 22
// 69.198 us; speedup vs baseline: 3.7329x; 1.0391x over previous
//
#include <hip/hip_runtime.h>
#include <hip/hip_bf16.h>

// Problem constants (shapes fixed by the reference)
#define XS   2
#define NP   96
#define NLAY 3
#define NXI  (XS*NP)   // 192
#define VBF_ARR (XS*256*96)   // 49152 ushorts per component array

// packed (rep,dim) index tables: 16 = 1+3+5+7 entries
__constant__ int P2R_c[16] = {0, 1,1,1, 2,2,2,2,2, 3,3,3,3,3,3,3};
__constant__ int P2D_c[16] = {0, 0,1,2, 0,1,2,3,4, 0,1,2,3,4,5,6};
__constant__ int DIMS_c[4] = {1,3,5,7};
__constant__ int OFF_c[4]  = {0,1,4,9};

typedef __attribute__((ext_vector_type(8))) short bf16x8;
typedef __attribute__((ext_vector_type(4))) float f32x4;

__device__ inline float2 cmadd(float2 acc, float2 a, float2 b){
    acc.x += a.x*b.x - a.y*b.y;
    acc.y += a.x*b.y + a.y*b.x;
    return acc;
}
__device__ inline unsigned short f2bf(float v){
    __hip_bfloat16 h = __float2bfloat16(v);
    union { __hip_bfloat16 h; unsigned short u; } cv; cv.h = h; return cv.u;
}
__device__ inline float bf2f(unsigned short u){
    union { unsigned short u; __hip_bfloat16 h; } cv; cv.u = u;
    return __bfloat162float(cv.h);
}

// Merged prep+filt kernel. Blocks [0,256): flat prep ranges
//   idx in [0,16384):  PKbf[6][qg][lm] bf16 hi/lo (S-phase A-operand)
//   idx in [16384,65536): Vbf0 pack: V -> bf16 hi/lo [arr][x][n=mtc][k=j]
// Blocks [256, 256+576): filters for (k, xi); cgf computed in-block (tiny).
__global__ __launch_bounds__(256)
void prep_filt_kernel(const float* __restrict__ cg,
                      const float* __restrict__ f,
                      const float* __restrict__ Vin,
                      const float* __restrict__ X,
                      unsigned short* __restrict__ PKbf,
                      unsigned short* __restrict__ Vbf0,
                      float* __restrict__ filt_g)      // [k][xi][96][16] complex
{
    __shared__ float2 cgf_s[784];
    __shared__ float2 dX_s[NP][7];

    const int tid = threadIdx.x;
    if (blockIdx.x < 256){
        int idx = blockIdx.x*256 + tid;
        if (idx < 16384){
            int id = idx;              // = qg*256 + lm
            int lm = id & 255;
            int qg = id >> 8;
            int ls = lm >> 4, mt = lm & 15;
            int qr = qg >> 2, g = qg & 3;
            int l = P2R_c[ls], s = P2D_c[ls];
            int m = P2R_c[mt], t = P2D_c[mt];
            int q = P2R_c[qr], r = P2D_c[qr];
            size_t co = (((((((size_t)g*4 + l)*7 + s)*4 + m)*7 + t)*4 + q)*7 + r);
            float re = cg[co*2], im = cg[co*2+1];
            unsigned short rh = f2bf(re), rl = f2bf(re - bf2f(rh));
            unsigned short ih = f2bf(im), il = f2bf(im - bf2f(ih));
            PKbf[0*16384 + id] = rh;
            PKbf[1*16384 + id] = rl;
            PKbf[2*16384 + id] = ih;
            PKbf[3*16384 + id] = il;
            PKbf[4*16384 + id] = ih ^ 0x8000;
            PKbf[5*16384 + id] = il ^ 0x8000;
        } else {
            int id = idx - 16384;      // = (x*256+n)*96 + kj
            int kj = id % 96;
            int n  = (id / 96) % 256;
            int x  = id / (96*256);
            int mt = n >> 4, c = n & 15;
            int m = P2R_c[mt], t = P2D_c[mt];
            const float* p = Vin + ((((size_t)(x*NP + kj)*4 + m)*16 + c)*7 + t)*2;
            float re = p[0], im = p[1];
            unsigned short h;
            h = f2bf(re); Vbf0[0*VBF_ARR + id] = h;
            Vbf0[1*VBF_ARR + id] = f2bf(re - bf2f(h));
            h = f2bf(im); Vbf0[2*VBF_ARR + id] = h;
            Vbf0[3*VBF_ARR + id] = f2bf(im - bf2f(h));
        }
        return;
    }

    // ---- filter blocks
    const int fb = blockIdx.x - 256;   // k*NXI + xi
    const int k  = fb / NXI;
    const int xi = fb % NXI;
    const int x = xi / NP, i = xi % NP;

    // compute cgf[k] in LDS (784 entries, 4 cmadd each)
    for (int u = tid; u < 784; u += 256){
        int qr = u / 49, st = u % 49;
        int s = st / 7, t = st % 7;
        int q = P2R_c[qr], r = P2D_c[qr];
        float2 acc = make_float2(0.f, 0.f);
        #pragma unroll
        for (int g = 0; g < 4; ++g){
            const float* cgp = cg + (((((((size_t)g*4+3)*7 + s)*4 + 3)*7 + t)*4 + q)*7 + r)*2;
            const float* fp  = f + ((k*4 + q)*4 + g)*2;
            acc = cmadd(acc, make_float2(cgp[0], cgp[1]), make_float2(fp[0], fp[1]));
        }
        cgf_s[u] = acc;
    }
    for (int e = tid; e < NP*7; e += 256){
        int j = e / 7, s = e % 7;
        const float* Xj = X + (((size_t)x*NP + j)*7 + s)*2;
        const float* Xi = X + (((size_t)x*NP + i)*7 + s)*2;
        dX_s[j][s] = make_float2(Xj[0]-Xi[0], Xj[1]-Xi[1]);
    }
    __syncthreads();

    float2* out = (float2*)filt_g + (size_t)fb*NP*16;
    for (int e = tid; e < NP*16; e += 256){
        int j = e >> 4, qr = e & 15;
        const float2* cb = cgf_s + qr*49;
        float2 acc = make_float2(0.f, 0.f);
        #pragma unroll
        for (int s = 0; s < 7; ++s){
            float2 inner = make_float2(0.f, 0.f);
            #pragma unroll
            for (int t = 0; t < 7; ++t)
                inner = cmadd(inner, cb[s*7 + t], dX_s[j][t]);
            acc = cmadd(acc, dX_s[j][s], inner);
        }
        if (qr >= 9){ float2 dv = dX_s[j][qr-9]; acc.x += dv.x; acc.y += dv.y; }
        out[e] = acc;
    }
}

// TS_kernel: one block per xi, 512 threads (8 waves). Both T and S on MFMA.
//  T: M16(ls) x K96(j) x N256(mtc) complex; A=filt (LDS), B=Vbf (global).
//  S: M64(qg) x K256(lm) x N16(c) complex; A=PKbf (global), B=T2buf (LDS).
//  W: VALU channel mix. LAST=0: emit next layer's Vbf operand.
//     LAST=1: write d_out directly (valid slots from (qr,d) threads; the 192
//     invalid r>=DIMS[q] slots zeroed by threads 256..447 - disjoint).
template<int LAST>
__global__ __launch_bounds__(512, 2)
void TS_kernel(const float* __restrict__ filt_gk,      // [xi][96][16] complex
               const unsigned short* __restrict__ PKbf,// [6][64][256] bf16
               const float* __restrict__ W_k,          // [q][c][g][d] complex
               const unsigned short* __restrict__ Vbf_in,  // [4][x][n][k] bf16
               unsigned short* __restrict__ Vbf_out,       // next layer (LAST=0)
               float* __restrict__ Dout)               // d_out (LAST=1)
{
    __shared__ __align__(16) unsigned short Abuf[6][16][104];  // 19968 B (aliased by S_s)
    __shared__ __align__(16) unsigned short T2buf[4][16][264]; // 33792 B
    float2* S_s = (float2*)&Abuf[0][0][0];                     // [qg][c] = 8192 B

    const int tid = threadIdx.x;
    const int xi = blockIdx.x;
    const int x = xi / NP, i = xi % NP;

    // build bf16 hi/lo A-operands from fp32 filters (L2-hot, 12 KB)
    for (int e = tid; e < NP*16; e += 512){
        const int j = e >> 4, ls = e & 15;
        float2 fv = ((const float2*)filt_gk)[((size_t)xi*NP + j)*16 + ls];
        unsigned short h = f2bf(fv.x);
        Abuf[0][ls][j] = h;
        Abuf[1][ls][j] = f2bf(fv.x - bf2f(h));
        h = f2bf(fv.y);
        unsigned short lo = f2bf(fv.y - bf2f(h));
        Abuf[2][ls][j] = h;
        Abuf[3][ls][j] = lo;
        Abuf[4][ls][j] = h  ^ 0x8000;   // -Fi (exact)
        Abuf[5][ls][j] = lo ^ 0x8000;
    }
    __syncthreads();

    const int w    = tid >> 6;
    const int lane = tid & 63;
    const int lrow = lane & 15;          // A row / B col / D col
    const int kb   = (lane >> 4) * 8;    // k sub-offset within K=32 step

    // ---- phase T (MFMA): T[ls][n] = sum_j F[j][ls]*V[j][n] (complex)
    {
        f32x4 accR[2], accI[2];
        #pragma unroll
        for (int nt = 0; nt < 2; ++nt){
            accR[nt] = (f32x4){0.f,0.f,0.f,0.f};
            accI[nt] = (f32x4){0.f,0.f,0.f,0.f};
        }
        const unsigned short* Vrh = Vbf_in + 0*VBF_ARR + (size_t)x*256*96;
        const unsigned short* Vrl = Vbf_in + 1*VBF_ARR + (size_t)x*256*96;
        const unsigned short* Vih = Vbf_in + 2*VBF_ARR + (size_t)x*256*96;
        const unsigned short* Vil = Vbf_in + 3*VBF_ARR + (size_t)x*256*96;
        #pragma unroll
        for (int kt = 0; kt < 3; ++kt){
            const int ka = kt*32 + kb;
            bf16x8 frh = *(const bf16x8*)&Abuf[0][lrow][ka];
            bf16x8 frl = *(const bf16x8*)&Abuf[1][lrow][ka];
            bf16x8 fih = *(const bf16x8*)&Abuf[2][lrow][ka];
            bf16x8 fil = *(const bf16x8*)&Abuf[3][lrow][ka];
            bf16x8 nfh = *(const bf16x8*)&Abuf[4][lrow][ka];
            bf16x8 nfl = *(const bf16x8*)&Abuf[5][lrow][ka];
            #pragma unroll
            for (int nt = 0; nt < 2; ++nt){
                const int n = w*32 + nt*16 + lrow;
                const size_t bo = (size_t)n*96 + ka;
                bf16x8 vrh = *(const bf16x8*)(Vrh + bo);
                bf16x8 vrl = *(const bf16x8*)(Vrl + bo);
                bf16x8 vih = *(const bf16x8*)(Vih + bo);
                bf16x8 vil = *(const bf16x8*)(Vil + bo);
                accR[nt] = __builtin_amdgcn_mfma_f32_16x16x32_bf16(frh, vrh, accR[nt], 0,0,0);
                accR[nt] = __builtin_amdgcn_mfma_f32_16x16x32_bf16(frh, vrl, accR[nt], 0,0,0);
                accR[nt] = __builtin_amdgcn_mfma_f32_16x16x32_bf16(frl, vrh, accR[nt], 0,0,0);
                accR[nt] = __builtin_amdgcn_mfma_f32_16x16x32_bf16(nfh, vih, accR[nt], 0,0,0);
                accR[nt] = __builtin_amdgcn_mfma_f32_16x16x32_bf16(nfh, vil, accR[nt], 0,0,0);
                accR[nt] = __builtin_amdgcn_mfma_f32_16x16x32_bf16(nfl, vih, accR[nt], 0,0,0);
                accI[nt] = __builtin_amdgcn_mfma_f32_16x16x32_bf16(frh, vih, accI[nt], 0,0,0);
                accI[nt] = __builtin_amdgcn_mfma_f32_16x16x32_bf16(frh, vil, accI[nt], 0,0,0);
                accI[nt] = __builtin_amdgcn_mfma_f32_16x16x32_bf16(frl, vih, accI[nt], 0,0,0);
                accI[nt] = __builtin_amdgcn_mfma_f32_16x16x32_bf16(fih, vrh, accI[nt], 0,0,0);
                accI[nt] = __builtin_amdgcn_mfma_f32_16x16x32_bf16(fih, vrl, accI[nt], 0,0,0);
                accI[nt] = __builtin_amdgcn_mfma_f32_16x16x32_bf16(fil, vrh, accI[nt], 0,0,0);
            }
        }
        // store straight to bf16 hi/lo B-operand: c = lrow, lm = ls*16 + mt
        #pragma unroll
        for (int nt = 0; nt < 2; ++nt){
            #pragma unroll
            for (int r = 0; r < 4; ++r){
                const int lmp = ((lane>>4)*4 + r)*16 + (w*2 + nt);
                float tr = accR[nt][r], ti = accI[nt][r];
                unsigned short h = f2bf(tr);
                T2buf[0][lrow][lmp] = h;
                T2buf[1][lrow][lmp] = f2bf(tr - bf2f(h));
                h = f2bf(ti);
                T2buf[2][lrow][lmp] = h;
                T2buf[3][lrow][lmp] = f2bf(ti - bf2f(h));
            }
        }
    }
    __syncthreads();

    // ---- phase S (MFMA): S[qg][c] = sum_lm PK^T[qg][lm] * T2[lm][c] (complex)
    {
        const int qtile = w & 3;
        const int kh    = w >> 2;
        f32x4 sR = (f32x4){0.f,0.f,0.f,0.f};
        f32x4 sI = (f32x4){0.f,0.f,0.f,0.f};
        #pragma unroll
        for (int kt4 = 0; kt4 < 4; ++kt4){
            const int kt = kh*4 + kt4;
            const int ka = kt*32 + kb;
            const size_t arow = (size_t)(qtile*16 + lrow)*256 + ka;
            bf16x8 prh = *(const bf16x8*)(PKbf + 0*16384 + arow);
            bf16x8 prl = *(const bf16x8*)(PKbf + 1*16384 + arow);
            bf16x8 pih = *(const bf16x8*)(PKbf + 2*16384 + arow);
            bf16x8 pil = *(const bf16x8*)(PKbf + 3*16384 + arow);
            bf16x8 pnh = *(const bf16x8*)(PKbf + 4*16384 + arow);
            bf16x8 pnl = *(const bf16x8*)(PKbf + 5*16384 + arow);
            bf16x8 trh = *(const bf16x8*)&T2buf[0][lrow][ka];
            bf16x8 trl = *(const bf16x8*)&T2buf[1][lrow][ka];
            bf16x8 tih = *(const bf16x8*)&T2buf[2][lrow][ka];
            bf16x8 til = *(const bf16x8*)&T2buf[3][lrow][ka];
            sR = __builtin_amdgcn_mfma_f32_16x16x32_bf16(prh, trh, sR, 0,0,0);
            sR = __builtin_amdgcn_mfma_f32_16x16x32_bf16(prh, trl, sR, 0,0,0);
            sR = __builtin_amdgcn_mfma_f32_16x16x32_bf16(prl, trh, sR, 0,0,0);
            sR = __builtin_amdgcn_mfma_f32_16x16x32_bf16(pnh, tih, sR, 0,0,0);
            sR = __builtin_amdgcn_mfma_f32_16x16x32_bf16(pnh, til, sR, 0,0,0);
            sR = __builtin_amdgcn_mfma_f32_16x16x32_bf16(pnl, tih, sR, 0,0,0);
            sI = __builtin_amdgcn_mfma_f32_16x16x32_bf16(prh, tih, sI, 0,0,0);
            sI = __builtin_amdgcn_mfma_f32_16x16x32_bf16(prh, til, sI, 0,0,0);
            sI = __builtin_amdgcn_mfma_f32_16x16x32_bf16(prl, tih, sI, 0,0,0);
            sI = __builtin_amdgcn_mfma_f32_16x16x32_bf16(pih, trh, sI, 0,0,0);
            sI = __builtin_amdgcn_mfma_f32_16x16x32_bf16(pih, trl, sI, 0,0,0);
            sI = __builtin_amdgcn_mfma_f32_16x16x32_bf16(pil, trh, sI, 0,0,0);
        }
        // staged K-half reduction into S_s[qg*16 + c]  (S_s aliases dead Abuf)
        if (kh == 0){
            #pragma unroll
            for (int r = 0; r < 4; ++r)
                S_s[((size_t)qtile*16 + (lane>>4)*4 + r)*16 + lrow] =
                    make_float2(sR[r], sI[r]);
        }
        __syncthreads();
        if (kh == 1){
            #pragma unroll
            for (int r = 0; r < 4; ++r){
                const size_t si = ((size_t)qtile*16 + (lane>>4)*4 + r)*16 + lrow;
                float2 sp = S_s[si];
                sp.x += sR[r]; sp.y += sI[r];
                S_s[si] = sp;
            }
        }
        __syncthreads();
    }

    // ---- phase W: out[qr][d] = sum_{c,g} S[qr*4+g][c]*W[q][c][g][d]
    if (tid < 256){
        const int qr2 = tid >> 4, d = tid & 15;
        const int q = P2R_c[qr2];
        float2 acc = make_float2(0.f, 0.f);
        const float2* Wb = (const float2*)W_k + (size_t)q*16*4*16 + d;
        #pragma unroll 4
        for (int c = 0; c < 16; ++c){
            #pragma unroll
            for (int g = 0; g < 4; ++g){
                acc = cmadd(acc, S_s[((size_t)qr2*4 + g)*16 + c], Wb[(c*4 + g)*16]);
            }
        }
        if (LAST){
            const int r = P2D_c[qr2];
            ((float2*)Dout)[((size_t)xi*4 + q)*112 + d*7 + r] = acc;
        } else {
            const size_t vo = ((size_t)x*256 + tid)*96 + i;
            unsigned short h;
            h = f2bf(acc.x); Vbf_out[0*VBF_ARR + vo] = h;
            Vbf_out[1*VBF_ARR + vo] = f2bf(acc.x - bf2f(h));
            h = f2bf(acc.y); Vbf_out[2*VBF_ARR + vo] = h;
            Vbf_out[3*VBF_ARR + vo] = f2bf(acc.y - bf2f(h));
        }
    } else if (LAST){
        // zero the 192 invalid (r >= DIMS[q]) slots; disjoint from valid writes
        const int u = tid - 256;
        if (u < 192){
            int q, base, span;
            if (u < 96)      { q = 0; base = 0;   span = 6; }
            else if (u < 160){ q = 1; base = 96;  span = 4; }
            else             { q = 2; base = 160; span = 2; }
            const int v = u - base;
            const int d = v / span;
            const int r = DIMS_c[q] + v % span;
            ((float2*)Dout)[((size_t)xi*4 + q)*112 + d*7 + r] = make_float2(0.f, 0.f);
        }
    }
}

extern "C" void kernel_launch(void* const* d_in, const int* in_sizes, int n_in,
                              void* d_out, int out_size, void* d_ws, size_t ws_size,
                              hipStream_t stream) {
    const float* X  = (const float*)d_in[0];
    // d_in[1] is 'l' (always 3, hardcoded)
    const float* V  = (const float*)d_in[2];
    const float* cg = (const float*)d_in[3];
    const float* f  = (const float*)d_in[4];
    const float* W  = (const float*)d_in[5];
    // d_in[6] is C4 (plain complex product, hardcoded)

    // ws layout (floats): PKbf 49152 | VbfA 98304 | VbfB 98304 | filt_g 1769472
    float* ws    = (float*)d_ws;
    unsigned short* PKbf = (unsigned short*)ws;
    unsigned short* VbfA = (unsigned short*)(ws + 49152);
    unsigned short* VbfB = (unsigned short*)(ws + 49152 + 98304);
    float* filt_g = ws + 49152 + 98304 + 98304;

    prep_filt_kernel<<<256 + NLAY*NXI, 256, 0, stream>>>(cg, f, V, X, PKbf, VbfA, filt_g);

    const float* W0 = W;
    const float* W1 = W + (size_t)1*4*16*4*16*2;
    const float* W2 = W + (size_t)2*4*16*4*16*2;
    const float* f0 = filt_g;
    const float* f1 = filt_g + (size_t)1*NXI*NP*16*2;
    const float* f2 = filt_g + (size_t)2*NXI*NP*16*2;

    TS_kernel<0><<<NXI, 512, 0, stream>>>(f0, PKbf, W0, VbfA, VbfB, nullptr);
    TS_kernel<0><<<NXI, 512, 0, stream>>>(f1, PKbf, W1, VbfB, VbfA, nullptr);
    TS_kernel<1><<<NXI, 512, 0, stream>>>(f2, PKbf, W2, VbfA, VbfB, (float*)d_out);
}